// Round 11
// baseline (2799.894 us; speedup 1.0000x reference)
//
#include <hip/hip_runtime.h>
#include <math.h>

#define SEQ 200

typedef float f32x4 __attribute__((ext_vector_type(4)));
typedef short bf16x8 __attribute__((ext_vector_type(8)));

__device__ __forceinline__ float sigmoidf_(float x) { return 1.0f / (1.0f + __expf(-x)); }

__device__ __forceinline__ unsigned short bf16_rn(float v) {
    unsigned x = __float_as_uint(v);
    unsigned r = x + 0x7FFFu + ((x >> 16) & 1u);
    return (unsigned short)(r >> 16);
}
__device__ __forceinline__ float bf16_to_f(unsigned short h) {
    return __uint_as_float(((unsigned)h) << 16);
}
__device__ __forceinline__ void cvt_hl(float v, unsigned short& h, unsigned short& l) {
    h = bf16_rn(v);
    l = bf16_rn(v - bf16_to_f(h));
}

// ---------------- Wt prep: Wt_h/Wt_l[1024 rc][448 k] bf16 ----------------
// rc = hj*64 + lc (hj 0..15); gcol = (lc>>4)*256 + hj*16 + (lc&15).
__global__ void prep_wt(const float* __restrict__ W_ih, const float* __restrict__ W_hh,
                        unsigned short* __restrict__ Wt_h, unsigned short* __restrict__ Wt_l) {
    int rc = blockIdx.x;
    int hj = rc >> 6, lc = rc & 63;
    int gcol = (lc >> 4) * 256 + hj * 16 + (lc & 15);
    for (int k = threadIdx.x; k < 448; k += 256) {
        float v = 0.f;
        if (k < 175) v = W_ih[(size_t)k * 1024 + gcol];
        else if (k >= 176 && k < 432) v = W_hh[(size_t)(k - 176) * 1024 + gcol];
        unsigned short h, l; cvt_hl(v, h, l);
        Wt_h[(size_t)rc * 448 + k] = h;
        Wt_l[(size_t)rc * 448 + k] = l;
    }
}

// ---------------- Wt_o prep: [256 rc = hj*16+c][256 k] bf16 h/l ----------------
// c<6: out col hj*6+c (15*6=90 exactly); c=6,7: pred cols 88,89; else zero.
__global__ void prep_wo(const float* __restrict__ W_out,
                        unsigned short* __restrict__ Wt_oh, unsigned short* __restrict__ Wt_ol) {
    int rc = blockIdx.x;
    int hj = rc >> 4, c = rc & 15;
    int col = (c < 6) ? (hj * 6 + c) : (c < 8 ? 82 + c : 999);
    for (int k = threadIdx.x; k < 256; k += 256) {
        float v = (col < 90) ? W_out[(size_t)k * 90 + col] : 0.f;
        unsigned short h, l; cvt_hl(v, h, l);
        Wt_oh[(size_t)rc * 256 + k] = h;
        Wt_ol[(size_t)rc * 256 + k] = l;
    }
}

// ---------------- Encoder -> xin_h[t][b][176] bf16 (32-batch, 3 blocks/CU) ----
__global__ __launch_bounds__(256, 3) void enc_kernel(
    const float* __restrict__ coords,
    const float* __restrict__ W_e1, const float* __restrict__ b_e1,
    const float* __restrict__ W_e2, const float* __restrict__ b_e2,
    unsigned short* __restrict__ xin_h)
{
    __shared__ float C[32][45];
    __shared__ float H[32][2][65];
    __shared__ float W2[64][64];
    __shared__ unsigned short O16[128][34];

    int t  = blockIdx.x >> 5;
    int bc = blockIdx.x & 31;
    int tid = threadIdx.x;

    for (int idx = tid; idx < 32 * 44; idx += 256) {
        int bl = idx / 44, j = idx - bl * 44;
        C[bl][j] = coords[((size_t)(bc * 32 + bl) * SEQ + t) * 88 + (j >> 1) * 4 + (j & 1)];
    }
    for (int idx = tid; idx < 64 * 64; idx += 256)
        W2[idx >> 6][idx & 63] = W_e2[idx];
    __syncthreads();

    {   // phase A
        int b  = tid >> 3;
        int cq = (tid & 7) * 8;
        float w0[8], w1[8], bb[8];
#pragma unroll
        for (int c = 0; c < 8; c++) { w0[c] = W_e1[cq + c]; w1[c] = W_e1[64 + cq + c]; bb[c] = b_e1[cq + c]; }
        for (int tm = 0; tm < 2; tm++) {
            float acc[8];
#pragma unroll
            for (int c = 0; c < 8; c++) acc[c] = 0.f;
            for (int p = 0; p < 11; p++) {
                float x = C[b][tm * 22 + p * 2];
                float y = C[b][tm * 22 + p * 2 + 1];
#pragma unroll
                for (int c = 0; c < 8; c++) {
                    float h = fmaf(x, w0[c], fmaf(y, w1[c], bb[c]));
                    acc[c] += fmaxf(h, 0.f);
                }
            }
#pragma unroll
            for (int c = 0; c < 8; c++) H[b][tm][cq + c] = acc[c] * (1.0f / 11.0f);
        }
    }
    __syncthreads();

    {   // phase B
        int b  = tid >> 3;
        int tm = (tid >> 2) & 1;
        int ch = (tid & 3) * 16;
        float acc[16];
#pragma unroll
        for (int c = 0; c < 16; c++) acc[c] = 0.f;
        for (int k = 0; k < 64; k++) {
            float h = H[b][tm][k];
#pragma unroll
            for (int c = 0; c < 16; c++) acc[c] = fmaf(h, W2[k][ch + c], acc[c]);
        }
#pragma unroll
        for (int c = 0; c < 16; c++)
            O16[tm * 64 + ch + c][b] = bf16_rn(acc[c] + b_e2[ch + c]);
    }
    __syncthreads();

    unsigned short* xrow = xin_h + ((size_t)t * 1024 + bc * 32) * 176;
    for (int idx = tid; idx < 32 * 22; idx += 256) {
        int bl = idx / 22, oct = idx - bl * 22;
        unsigned short hs[8];
#pragma unroll
        for (int e = 0; e < 8; e++) {
            int k = oct * 8 + e;
            if (k < 44)       hs[e] = bf16_rn(C[bl][k]);
            else if (k < 172) hs[e] = O16[k - 44][bl];
            else              hs[e] = 0;
        }
        uint4 pk;
        pk.x = (unsigned)hs[0] | ((unsigned)hs[1] << 16);
        pk.y = (unsigned)hs[2] | ((unsigned)hs[3] << 16);
        pk.z = (unsigned)hs[4] | ((unsigned)hs[5] << 16);
        pk.w = (unsigned)hs[6] | ((unsigned)hs[7] << 16);
        *(uint4*)(xrow + (size_t)bl * 176 + oct * 8) = pk;
    }
}

#define MFMA_B(d, a, b) d = __builtin_amdgcn_mfma_f32_16x16x32_bf16(a, b, d, 0, 0, 0)

// ---------------- Per-step kernel (consumer-only, barrier-free K-loop) --------
// grid 512 = 32 bi x 16 hj (N=64 gate cols/block), 256 threads (4 waves x 16 cols).
// B has zero intra-block reuse -> no LDS staging: each wave reads its B fragments
// directly from global (L2-resident), fully unrolled. LDS 67KB -> 2 blocks/CU.
__global__ __launch_bounds__(256, 2) void step_kernel(
    int t,
    const unsigned short* __restrict__ xin_h,
    const unsigned short* __restrict__ hxh_in, const unsigned short* __restrict__ hxl_in,
    unsigned short* __restrict__ hxh_out, unsigned short* __restrict__ hxl_out,
    float* __restrict__ cx,
    const unsigned short* __restrict__ Wt_h, const unsigned short* __restrict__ Wt_l,
    const unsigned short* __restrict__ Wt_oh, const unsigned short* __restrict__ Wt_ol,
    const float* __restrict__ b_ih, const float* __restrict__ b_hh,
    const float* __restrict__ b_out,
    const float* __restrict__ pitch, float* __restrict__ d_out)
{
    __shared__ unsigned short AH[32 * 456];   // 29184 B
    __shared__ unsigned short AL[32 * 456];   // 29184 B
    __shared__ float U[2112];                 // 8448 B: out partials (2048) / G gates (64x33)
    __shared__ float predL[32][2];            // 256 B

    int tid = threadIdx.x;
    int bi = blockIdx.x & 31, hj = blockIdx.x >> 5;   // hj 0..15
    int bg0 = bi * 32;
    int l = tid & 63, w = tid >> 6;                   // w 0..3
    int lr = l & 15, qa = l >> 4;

    const unsigned short* wbh = Wt_h + (size_t)(hj * 64) * 448;
    const unsigned short* wbl = Wt_l + (size_t)(hj * 64) * 448;

    // ---- stage ----
    for (int idx = tid; idx < 32 * 32; idx += 256) {   // hx rows 176..431 (always)
        int b = idx >> 5, oct = idx & 31;
        *(uint4*)&AH[b * 456 + 176 + oct * 8] =
            *(const uint4*)(hxh_in + (size_t)(bg0 + b) * 256 + oct * 8);
        *(uint4*)&AL[b * 456 + 176 + oct * 8] =
            *(const uint4*)(hxl_in + (size_t)(bg0 + b) * 256 + oct * 8);
    }
    if (t < SEQ) {
        const unsigned short* xr = xin_h + ((size_t)t * 1024 + bg0) * 176;
        for (int idx = tid; idx < 32 * 22; idx += 256) {     // x rows 0..175
            int b = idx / 22, oct = idx - b * 22;
            *(uint4*)&AH[b * 456 + oct * 8] = *(const uint4*)(xr + (size_t)b * 176 + oct * 8);
        }
        if (tid < 64) {   // AL k160..175 zero; AH/AL tails k432..447 zero
            int b = tid >> 1, h8 = (tid & 1) * 8;
            *(uint4*)&AL[b * 456 + 160 + h8] = make_uint4(0, 0, 0, 0);
            *(uint4*)&AH[b * 456 + 432 + h8] = make_uint4(0, 0, 0, 0);
            *(uint4*)&AL[b * 456 + 432 + h8] = make_uint4(0, 0, 0, 0);
        }
    }
    __syncthreads();   // B1

    // ---- out-MFMA: ext tile = 16 cols (6 out + 2 pred + 8 zero), wave w = K-quarter ----
    {
        const unsigned short* woh = Wt_oh + ((size_t)(hj * 16 + lr)) * 256 + w * 64 + qa * 8;
        const unsigned short* wol = Wt_ol + ((size_t)(hj * 16 + lr)) * 256 + w * 64 + qa * 8;
        bf16x8 bh0 = *(const bf16x8*)(woh);
        bf16x8 bl0 = *(const bf16x8*)(wol);
        bf16x8 bh1 = *(const bf16x8*)(woh + 32);
        bf16x8 bl1 = *(const bf16x8*)(wol + 32);
        f32x4 acce[2];
        acce[0] = (f32x4){0.f, 0.f, 0.f, 0.f};
        acce[1] = (f32x4){0.f, 0.f, 0.f, 0.f};
#pragma unroll
        for (int ks2 = 0; ks2 < 2; ks2++) {
            bf16x8 bh = ks2 ? bh1 : bh0;
            bf16x8 bl = ks2 ? bl1 : bl0;
#pragma unroll
            for (int mt = 0; mt < 2; mt++) {
                bf16x8 ah = *(const bf16x8*)&AH[(mt * 16 + lr) * 456 + 176 + w * 64 + ks2 * 32 + qa * 8];
                bf16x8 al = *(const bf16x8*)&AL[(mt * 16 + lr) * 456 + 176 + w * 64 + ks2 * 32 + qa * 8];
                MFMA_B(acce[mt], ah, bh);
                MFMA_B(acce[mt], ah, bl);
                MFMA_B(acce[mt], al, bh);
            }
        }
#pragma unroll
        for (int mt = 0; mt < 2; mt++)
#pragma unroll
            for (int r = 0; r < 4; r++)
                U[w * 512 + (mt * 16 + qa * 4 + r) * 16 + lr] = acce[mt][r];
    }
    __syncthreads();   // B2

    // ---- reduce partials; write out_{t-1}; pred -> predL ----
    for (int idx = tid; idx < 512; idx += 256) {
        int b = idx >> 4, c = idx & 15;
        float v = U[idx] + U[512 + idx] + U[1024 + idx] + U[1536 + idx];
        if (c < 8) {
            int col = (c < 6) ? (hj * 6 + c) : (82 + c);
            if (col < 90) {
                if (t > 0) {
                    float vv = (v + b_out[col]) * pitch[c & 1];
                    if (c < 6) d_out[((size_t)(bg0 + b) * SEQ + (t - 1)) * 90 + col] = vv;
                    else predL[b][c - 6] = vv;
                } else if (c >= 6) {
                    predL[b][c - 6] = 0.f;
                }
            }
        }
    }
    __syncthreads();   // B3

    if (t < SEQ) {
        // ---- closest distance; fill A rows 172..174 ----
        if (tid < 32) {
            int b = tid;
            float p0 = predL[b][0], p1 = predL[b][1];
            float m = 1e30f;
#pragma unroll
            for (int p = 0; p < 22; p++) {
                float px = bf16_to_f(AH[b * 456 + 2 * p]);
                float py = bf16_to_f(AH[b * 456 + 2 * p + 1]);
                float dx = p0 - px, dy = p1 - py;
                m = fminf(m, fmaf(dx, dx, dy * dy));
            }
            unsigned short h, lo;
            cvt_hl(sqrtf(m), h, lo); AH[b * 456 + 172] = h; AL[b * 456 + 172] = lo;
            cvt_hl(p0, h, lo);       AH[b * 456 + 173] = h; AL[b * 456 + 173] = lo;
            cvt_hl(p1, h, lo);       AH[b * 456 + 174] = h; AL[b * 456 + 174] = lo;
        }
        __syncthreads();   // B4

        // ---- K-loop: 14 x K=32, fully unrolled, B direct from global, NO barriers ----
        {
            f32x4 acc[2];
            acc[0] = (f32x4){0.f, 0.f, 0.f, 0.f};
            acc[1] = (f32x4){0.f, 0.f, 0.f, 0.f};
#pragma unroll
            for (int ks = 0; ks < 14; ks++) {
                bf16x8 ah0 = *(const bf16x8*)&AH[(lr) * 456 + ks * 32 + qa * 8];
                bf16x8 ah1 = *(const bf16x8*)&AH[(16 + lr) * 456 + ks * 32 + qa * 8];
                bf16x8 bh = *(const bf16x8*)(wbh + (size_t)(w * 16 + lr) * 448 + ks * 32 + qa * 8);
                bf16x8 bl = *(const bf16x8*)(wbl + (size_t)(w * 16 + lr) * 448 + ks * 32 + qa * 8);
                MFMA_B(acc[0], ah0, bh);
                MFMA_B(acc[0], ah0, bl);
                MFMA_B(acc[1], ah1, bh);
                MFMA_B(acc[1], ah1, bl);
                if (ks >= 5) {
                    bf16x8 al0 = *(const bf16x8*)&AL[(lr) * 456 + ks * 32 + qa * 8];
                    bf16x8 al1 = *(const bf16x8*)&AL[(16 + lr) * 456 + ks * 32 + qa * 8];
                    MFMA_B(acc[0], al0, bh);
                    MFMA_B(acc[1], al1, bh);
                }
            }
            // ---- G exchange: U[64 col][33] ----
#pragma unroll
            for (int mt = 0; mt < 2; mt++)
#pragma unroll
                for (int r = 0; r < 4; r++)
                    U[(w * 16 + lr) * 33 + (mt * 16 + qa * 4 + r)] = acc[mt][r];
        }
        __syncthreads();   // B5

        // ---- LSTM pointwise: 16 hidden cols/block, 2 per thread ----
        {
            int b = tid & 31, hq = tid >> 5;   // hq 0..7
            unsigned short hh2[2], hl2[2];
#pragma unroll
            for (int q = 0; q < 2; q++) {
                int hlc = hq * 2 + q;          // 0..15
                int gb = hj * 16 + hlc;
                float iv = U[(0 * 16 + hlc) * 33 + b] + b_ih[gb]        + b_hh[gb];
                float fv = U[(1 * 16 + hlc) * 33 + b] + b_ih[256 + gb]  + b_hh[256 + gb];
                float gv = U[(2 * 16 + hlc) * 33 + b] + b_ih[512 + gb]  + b_hh[512 + gb];
                float ov = U[(3 * 16 + hlc) * 33 + b] + b_ih[768 + gb]  + b_hh[768 + gb];
                size_t cidx = (size_t)gb * 1024 + bg0 + b;
                float c_old = cx[cidx];
                float c_new = fmaf(sigmoidf_(fv), c_old, sigmoidf_(iv) * tanhf(gv));
                cx[cidx] = c_new;
                float hv = sigmoidf_(ov) * tanhf(c_new);
                cvt_hl(hv, hh2[q], hl2[q]);
            }
            size_t ho = (size_t)(bg0 + b) * 256 + hj * 16 + hq * 2;
            *(ushort2*)&hxh_out[ho] = make_ushort2(hh2[0], hh2[1]);
            *(ushort2*)&hxl_out[ho] = make_ushort2(hl2[0], hl2[1]);
        }
    }
}

extern "C" void kernel_launch(void* const* d_in, const int* in_sizes, int n_in,
                              void* d_out, int out_size, void* d_ws, size_t ws_size,
                              hipStream_t stream) {
    const float* coords = (const float*)d_in[0];
    const float* pitch  = (const float*)d_in[1];
    const float* W_e1   = (const float*)d_in[2];
    const float* b_e1   = (const float*)d_in[3];
    const float* W_e2   = (const float*)d_in[4];
    const float* b_e2   = (const float*)d_in[5];
    const float* W_ih   = (const float*)d_in[6];
    const float* b_ih   = (const float*)d_in[7];
    const float* W_hh   = (const float*)d_in[8];
    const float* b_hh   = (const float*)d_in[9];
    const float* W_out  = (const float*)d_in[10];
    const float* b_out  = (const float*)d_in[11];
    float* out = (float*)d_out;
    float* ws  = (float*)d_ws;

    // ws layout (float offsets); total ~19.3M floats ~= 77 MB
    float* cxb = ws;                                          // 262144
    unsigned short* hxhA = (unsigned short*)(ws + 262144);    // 131072 f
    unsigned short* hxlA = (unsigned short*)(ws + 393216);    // 131072 f
    unsigned short* hxhB = (unsigned short*)(ws + 524288);    // 131072 f
    unsigned short* hxlB = (unsigned short*)(ws + 655360);    // 131072 f
    unsigned short* Wt_h = (unsigned short*)(ws + 786432);    // 229376 f
    unsigned short* Wt_l = (unsigned short*)(ws + 1015808);   // 229376 f
    unsigned short* Wt_oh = (unsigned short*)(ws + 1245184);  // 32768 f
    unsigned short* Wt_ol = (unsigned short*)(ws + 1277952);  // 32768 f
    unsigned short* xin_h = (unsigned short*)(ws + 1310720);  // 18022400 f

    // zero cx + hxhA + hxlA (poisoned 0xAA by harness)
    hipMemsetAsync(ws, 0, (size_t)524288 * sizeof(float), stream);

    prep_wt<<<1024, 256, 0, stream>>>(W_ih, W_hh, Wt_h, Wt_l);
    prep_wo<<<256, 256, 0, stream>>>(W_out, Wt_oh, Wt_ol);
    enc_kernel<<<SEQ * 32, 256, 0, stream>>>(coords, W_e1, b_e1, W_e2, b_e2, xin_h);

    for (int t = 0; t <= SEQ; t++) {
        bool even = !(t & 1);
        step_kernel<<<512, 256, 0, stream>>>(
            t, xin_h,
            even ? hxhA : hxhB, even ? hxlA : hxlB,
            even ? hxhB : hxhA, even ? hxlB : hxlA,
            cxb, Wt_h, Wt_l, Wt_oh, Wt_ol, b_ih, b_hh, b_out, pitch, out);
    }
}

// Round 12
// 2655.933 us; speedup vs baseline: 1.0542x; 1.0542x over previous
//
#include <hip/hip_runtime.h>
#include <math.h>

#define SEQ 200

typedef float f32x4 __attribute__((ext_vector_type(4)));
typedef short bf16x8 __attribute__((ext_vector_type(8)));

__device__ __forceinline__ float sigmoidf_(float x) { return 1.0f / (1.0f + __expf(-x)); }

__device__ __forceinline__ unsigned short bf16_rn(float v) {
    unsigned x = __float_as_uint(v);
    unsigned r = x + 0x7FFFu + ((x >> 16) & 1u);
    return (unsigned short)(r >> 16);
}
__device__ __forceinline__ float bf16_to_f(unsigned short h) {
    return __uint_as_float(((unsigned)h) << 16);
}
__device__ __forceinline__ void cvt_hl(float v, unsigned short& h, unsigned short& l) {
    h = bf16_rn(v);
    l = bf16_rn(v - bf16_to_f(h));
}

// ---------------- Wt prep: Wt_h/Wt_l[1024 rc][448 k] bf16 ----------------
__global__ void prep_wt(const float* __restrict__ W_ih, const float* __restrict__ W_hh,
                        unsigned short* __restrict__ Wt_h, unsigned short* __restrict__ Wt_l) {
    int rc = blockIdx.x;
    int hj = rc >> 7, lc = rc & 127;
    int gcol = (lc >> 5) * 256 + hj * 32 + (lc & 31);
    for (int k = threadIdx.x; k < 448; k += 256) {
        float v = 0.f;
        if (k < 175) v = W_ih[(size_t)k * 1024 + gcol];
        else if (k >= 176 && k < 432) v = W_hh[(size_t)(k - 176) * 1024 + gcol];
        unsigned short h, l; cvt_hl(v, h, l);
        Wt_h[(size_t)rc * 448 + k] = h;
        Wt_l[(size_t)rc * 448 + k] = l;
    }
}

// ---------------- Wt_o prep: [128 rc = hj*16+c][256 k] bf16 h/l ----------------
__global__ void prep_wo(const float* __restrict__ W_out,
                        unsigned short* __restrict__ Wt_oh, unsigned short* __restrict__ Wt_ol) {
    int rc = blockIdx.x;
    int hj = rc >> 4, c = rc & 15;
    int col = (c < 12) ? (hj * 12 + c) : (c < 14 ? 76 + c : 999);
    for (int k = threadIdx.x; k < 256; k += 256) {
        float v = (col < 90) ? W_out[(size_t)k * 90 + col] : 0.f;
        unsigned short h, l; cvt_hl(v, h, l);
        Wt_oh[(size_t)rc * 256 + k] = h;
        Wt_ol[(size_t)rc * 256 + k] = l;
    }
}

// ---------------- Encoder -> xin_h[t][b][176] bf16 (32-batch, 5 blocks/CU) ----
// W_e2 read direct from global (L1-resident, bit-identical) -> LDS 47.6->31.4 KB.
__global__ __launch_bounds__(256, 5) void enc_kernel(
    const float* __restrict__ coords,
    const float* __restrict__ W_e1, const float* __restrict__ b_e1,
    const float* __restrict__ W_e2, const float* __restrict__ b_e2,
    unsigned short* __restrict__ xin_h)
{
    __shared__ float C[32][45];              // only the 44 used cols
    __shared__ float H[32][2][65];
    __shared__ unsigned short O16[128][34];  // bf16 (exact: output is bf16-rounded anyway)

    int t  = blockIdx.x >> 5;
    int bc = blockIdx.x & 31;
    int tid = threadIdx.x;

    for (int idx = tid; idx < 32 * 44; idx += 256) {
        int bl = idx / 44, j = idx - bl * 44;
        C[bl][j] = coords[((size_t)(bc * 32 + bl) * SEQ + t) * 88 + (j >> 1) * 4 + (j & 1)];
    }
    __syncthreads();

    {   // phase A
        int b  = tid >> 3;
        int cq = (tid & 7) * 8;
        float w0[8], w1[8], bb[8];
#pragma unroll
        for (int c = 0; c < 8; c++) { w0[c] = W_e1[cq + c]; w1[c] = W_e1[64 + cq + c]; bb[c] = b_e1[cq + c]; }
        for (int tm = 0; tm < 2; tm++) {
            float acc[8];
#pragma unroll
            for (int c = 0; c < 8; c++) acc[c] = 0.f;
            for (int p = 0; p < 11; p++) {
                float x = C[b][tm * 22 + p * 2];
                float y = C[b][tm * 22 + p * 2 + 1];
#pragma unroll
                for (int c = 0; c < 8; c++) {
                    float h = fmaf(x, w0[c], fmaf(y, w1[c], bb[c]));
                    acc[c] += fmaxf(h, 0.f);
                }
            }
#pragma unroll
            for (int c = 0; c < 8; c++) H[b][tm][cq + c] = acc[c] * (1.0f / 11.0f);
        }
    }
    __syncthreads();

    {   // phase B: W_e2 direct from global (bit-identical values)
        int b  = tid >> 3;
        int tm = (tid >> 2) & 1;
        int ch = (tid & 3) * 16;
        float acc[16];
#pragma unroll
        for (int c = 0; c < 16; c++) acc[c] = 0.f;
        for (int k = 0; k < 64; k++) {
            float h = H[b][tm][k];
            const float* w2row = W_e2 + k * 64 + ch;
#pragma unroll
            for (int c = 0; c < 16; c++) acc[c] = fmaf(h, w2row[c], acc[c]);
        }
#pragma unroll
        for (int c = 0; c < 16; c++)
            O16[tm * 64 + ch + c][b] = bf16_rn(acc[c] + b_e2[ch + c]);
    }
    __syncthreads();

    unsigned short* xrow = xin_h + ((size_t)t * 1024 + bc * 32) * 176;
    for (int idx = tid; idx < 32 * 22; idx += 256) {
        int bl = idx / 22, oct = idx - bl * 22;
        unsigned short hs[8];
#pragma unroll
        for (int e = 0; e < 8; e++) {
            int k = oct * 8 + e;
            if (k < 44)       hs[e] = bf16_rn(C[bl][k]);
            else if (k < 172) hs[e] = O16[k - 44][bl];
            else              hs[e] = 0;
        }
        uint4 pk;
        pk.x = (unsigned)hs[0] | ((unsigned)hs[1] << 16);
        pk.y = (unsigned)hs[2] | ((unsigned)hs[3] << 16);
        pk.z = (unsigned)hs[4] | ((unsigned)hs[5] << 16);
        pk.w = (unsigned)hs[6] | ((unsigned)hs[7] << 16);
        *(uint4*)(xrow + (size_t)bl * 176 + oct * 8) = pk;
    }
}

#define MFMA_B(d, a, b) d = __builtin_amdgcn_mfma_f32_16x16x32_bf16(a, b, d, 0, 0, 0)

#define P_LOAD(R0, R1, R2, R3, KO) \
    R0 = *(const uint4*)(wbh + (size_t)c0 * 448 + (KO) + oct * 8); \
    R1 = *(const uint4*)(wbl + (size_t)c0 * 448 + (KO) + oct * 8); \
    R2 = *(const uint4*)(wbh + (size_t)c1 * 448 + (KO) + oct * 8); \
    R3 = *(const uint4*)(wbl + (size_t)c1 * 448 + (KO) + oct * 8);

#define P_STORE(R0, R1, R2, R3, NB) \
    *(uint4*)&BB[NB][0][c0 * 40 + oct * 8] = R0; \
    *(uint4*)&BB[NB][1][c0 * 40 + oct * 8] = R1; \
    *(uint4*)&BB[NB][0][c1 * 40 + oct * 8] = R2; \
    *(uint4*)&BB[NB][1][c1 * 40 + oct * 8] = R3;

// ---------------- Per-step kernel (round-10 proven, byte-identical) ----------
// grid 256 x 512 threads: waves 0-3 compute (out-MFMA + gates K-loop),
// waves 4-7 stage B chunks via LDS 3-buffer pipeline (latency decoupling —
// round 11 measured direct-global B at +2.1 us/step).
__global__ __launch_bounds__(512, 1) void step_kernel(
    int t,
    const unsigned short* __restrict__ xin_h,
    const unsigned short* __restrict__ hxh_in, const unsigned short* __restrict__ hxl_in,
    unsigned short* __restrict__ hxh_out, unsigned short* __restrict__ hxl_out,
    float* __restrict__ cx,
    const unsigned short* __restrict__ Wt_h, const unsigned short* __restrict__ Wt_l,
    const unsigned short* __restrict__ Wt_oh, const unsigned short* __restrict__ Wt_ol,
    const float* __restrict__ b_ih, const float* __restrict__ b_hh,
    const float* __restrict__ b_out,
    const float* __restrict__ pitch, float* __restrict__ d_out)
{
    __shared__ unsigned short AH[32 * 456];        // 29184 B
    __shared__ unsigned short AL[32 * 456];        // 29184 B
    __shared__ unsigned short BB[3][2][128 * 40];  // 61440 B
    __shared__ float U[128 * 33];                  // 16896 B: out partials / G gates
    __shared__ float predL[32][2];                 // 256 B

    int tid = threadIdx.x;
    int bi = blockIdx.x & 31, hj = blockIdx.x >> 5;
    int bg0 = bi * 32;
    int l = tid & 63, w = (tid >> 6) & 3;
    int lr = l & 15, qa = l >> 4;

    const unsigned short* wbh = Wt_h + (size_t)(hj * 128) * 448;
    const unsigned short* wbl = Wt_l + (size_t)(hj * 128) * 448;

    // ---- stage ----
    for (int idx = tid; idx < 32 * 32; idx += 512) {   // hx rows 176..431 (always)
        int b = idx >> 5, oct = idx & 31;
        *(uint4*)&AH[b * 456 + 176 + oct * 8] =
            *(const uint4*)(hxh_in + (size_t)(bg0 + b) * 256 + oct * 8);
        *(uint4*)&AL[b * 456 + 176 + oct * 8] =
            *(const uint4*)(hxl_in + (size_t)(bg0 + b) * 256 + oct * 8);
    }
    if (t < SEQ) {
        const unsigned short* xr = xin_h + ((size_t)t * 1024 + bg0) * 176;
        for (int idx = tid; idx < 32 * 22; idx += 512) {     // x rows 0..175
            int b = idx / 22, oct = idx - b * 22;
            *(uint4*)&AH[b * 456 + oct * 8] = *(const uint4*)(xr + (size_t)b * 176 + oct * 8);
        }
        if (tid < 64) {   // AL k160..175 zero; AH/AL tails k432..447 zero
            int b = tid >> 1, h8 = (tid & 1) * 8;
            *(uint4*)&AL[b * 456 + 160 + h8] = make_uint4(0, 0, 0, 0);
            *(uint4*)&AH[b * 456 + 432 + h8] = make_uint4(0, 0, 0, 0);
            *(uint4*)&AL[b * 456 + 432 + h8] = make_uint4(0, 0, 0, 0);
        }
        {   // BB chunk 0
            int c = tid >> 2, o = tid & 3;
            *(uint4*)&BB[0][0][c * 40 + o * 8] = *(const uint4*)(wbh + (size_t)c * 448 + o * 8);
            *(uint4*)&BB[0][1][c * 40 + o * 8] = *(const uint4*)(wbl + (size_t)c * 448 + o * 8);
        }
    }
    __syncthreads();   // B1

    // ---- out-MFMA (waves 0-3) / producer prologue loads (waves 4-7) ----
    uint4 rA0, rA1, rA2, rA3, rB0, rB1, rB2, rB3;
    int c0 = (tid & 255) >> 2, oct = tid & 3, c1 = ((tid & 255) >> 2) + 64;
    if (tid < 256) {
        const unsigned short* woh = Wt_oh + ((size_t)(hj * 16 + lr)) * 256 + w * 64 + qa * 8;
        const unsigned short* wol = Wt_ol + ((size_t)(hj * 16 + lr)) * 256 + w * 64 + qa * 8;
        bf16x8 bh0 = *(const bf16x8*)(woh);
        bf16x8 bl0 = *(const bf16x8*)(wol);
        bf16x8 bh1 = *(const bf16x8*)(woh + 32);
        bf16x8 bl1 = *(const bf16x8*)(wol + 32);
        f32x4 acce[2];
        acce[0] = (f32x4){0.f, 0.f, 0.f, 0.f};
        acce[1] = (f32x4){0.f, 0.f, 0.f, 0.f};
#pragma unroll
        for (int ks2 = 0; ks2 < 2; ks2++) {
            bf16x8 bh = ks2 ? bh1 : bh0;
            bf16x8 bl = ks2 ? bl1 : bl0;
#pragma unroll
            for (int mt = 0; mt < 2; mt++) {
                bf16x8 ah = *(const bf16x8*)&AH[(mt * 16 + lr) * 456 + 176 + w * 64 + ks2 * 32 + qa * 8];
                bf16x8 al = *(const bf16x8*)&AL[(mt * 16 + lr) * 456 + 176 + w * 64 + ks2 * 32 + qa * 8];
                MFMA_B(acce[mt], ah, bh);
                MFMA_B(acce[mt], ah, bl);
                MFMA_B(acce[mt], al, bh);
            }
        }
#pragma unroll
        for (int mt = 0; mt < 2; mt++)
#pragma unroll
            for (int r = 0; r < 4; r++)
                U[w * 512 + (mt * 16 + qa * 4 + r) * 16 + lr] = acce[mt][r];
    } else if (t < SEQ) {
        P_LOAD(rA0, rA1, rA2, rA3, 32)    // chunk 1
        P_LOAD(rB0, rB1, rB2, rB3, 64)    // chunk 2
    }
    __syncthreads();   // B2

    // ---- reduce partials; write out_{t-1}; pred -> predL ----
    if (tid < 256) {
#pragma unroll
        for (int j = 0; j < 2; j++) {
            int i = tid * 2 + j;
            int b = i >> 4, c = i & 15;
            float v = U[i] + U[512 + i] + U[1024 + i] + U[1536 + i];
            if (c < 14) {
                int col = (c < 12) ? (hj * 12 + c) : (76 + c);
                if (col < 90) {
                    if (t > 0) {
                        float vv = (v + b_out[col]) * pitch[c & 1];
                        if (c < 12) d_out[((size_t)(bg0 + b) * SEQ + (t - 1)) * 90 + col] = vv;
                        else predL[b][c - 12] = vv;
                    } else if (c >= 12) {
                        predL[b][c - 12] = 0.f;
                    }
                }
            }
        }
    }
    __syncthreads();   // B3

    if (t < SEQ) {
        // ---- closest distance; fill A rows 172..174 ----
        if (tid < 32) {
            int b = tid;
            float p0 = predL[b][0], p1 = predL[b][1];
            float m = 1e30f;
#pragma unroll
            for (int p = 0; p < 22; p++) {
                float px = bf16_to_f(AH[b * 456 + 2 * p]);
                float py = bf16_to_f(AH[b * 456 + 2 * p + 1]);
                float dx = p0 - px, dy = p1 - py;
                m = fminf(m, fmaf(dx, dx, dy * dy));
            }
            unsigned short h, lo;
            cvt_hl(sqrtf(m), h, lo); AH[b * 456 + 172] = h; AL[b * 456 + 172] = lo;
            cvt_hl(p0, h, lo);       AH[b * 456 + 173] = h; AL[b * 456 + 173] = lo;
            cvt_hl(p1, h, lo);       AH[b * 456 + 174] = h; AL[b * 456 + 174] = lo;
        }
        __syncthreads();   // B4

        if (tid < 256) {
            // ---- consumer K-loop: 14 x K=32, fully unrolled, 3-buf ----
            f32x4 acc[2][2];
#pragma unroll
            for (int ct = 0; ct < 2; ct++)
#pragma unroll
                for (int mt = 0; mt < 2; mt++) acc[ct][mt] = (f32x4){0.f, 0.f, 0.f, 0.f};

#pragma unroll
            for (int ks = 0; ks < 14; ks++) {
                const int cur = ks % 3;
                bf16x8 ah[2], al[2], bh[2], bl[2];
#pragma unroll
                for (int mt = 0; mt < 2; mt++)
                    ah[mt] = *(const bf16x8*)&AH[(mt * 16 + lr) * 456 + ks * 32 + qa * 8];
                if (ks >= 5) {
#pragma unroll
                    for (int mt = 0; mt < 2; mt++)
                        al[mt] = *(const bf16x8*)&AL[(mt * 16 + lr) * 456 + ks * 32 + qa * 8];
                }
#pragma unroll
                for (int ct = 0; ct < 2; ct++) {
                    bh[ct] = *(const bf16x8*)&BB[cur][0][(w * 32 + ct * 16 + lr) * 40 + qa * 8];
                    bl[ct] = *(const bf16x8*)&BB[cur][1][(w * 32 + ct * 16 + lr) * 40 + qa * 8];
                }
#pragma unroll
                for (int ct = 0; ct < 2; ct++)
#pragma unroll
                    for (int mt = 0; mt < 2; mt++) {
                        MFMA_B(acc[ct][mt], ah[mt], bh[ct]);
                        MFMA_B(acc[ct][mt], ah[mt], bl[ct]);
                        if (ks >= 5) MFMA_B(acc[ct][mt], al[mt], bh[ct]);
                    }
                __syncthreads();
            }

            // ---- G exchange ----
#pragma unroll
            for (int ct = 0; ct < 2; ct++)
#pragma unroll
                for (int mt = 0; mt < 2; mt++)
#pragma unroll
                    for (int r = 0; r < 4; r++)
                        U[(w * 32 + ct * 16 + lr) * 33 + (mt * 16 + qa * 4 + r)] = acc[ct][mt][r];
        } else {
            // ---- producer loop: store chunk ks+1 (loaded 2 iters ago), issue ks+3 ----
#pragma unroll
            for (int ks = 0; ks < 14; ks++) {
                if (ks <= 12) {
                    const int nb = (ks + 1) % 3;
                    if ((ks & 1) == 0) { P_STORE(rA0, rA1, rA2, rA3, nb) }
                    else               { P_STORE(rB0, rB1, rB2, rB3, nb) }
                }
                if (ks <= 10) {
                    const int ko = (ks + 3) * 32;
                    if ((ks & 1) == 0) { P_LOAD(rA0, rA1, rA2, rA3, ko) }
                    else               { P_LOAD(rB0, rB1, rB2, rB3, ko) }
                }
                __syncthreads();
            }
        }
        __syncthreads();   // B5

        // ---- LSTM pointwise ----
        if (tid < 256) {
            int b = tid & 31, hq = tid >> 5;
            unsigned short hh[4], hl[4];
#pragma unroll
            for (int q = 0; q < 4; q++) {
                int hlc = hq * 4 + q;
                int gb = hj * 32 + hlc;
                float iv = U[(0 * 32 + hlc) * 33 + b] + b_ih[gb]        + b_hh[gb];
                float fv = U[(1 * 32 + hlc) * 33 + b] + b_ih[256 + gb]  + b_hh[256 + gb];
                float gv = U[(2 * 32 + hlc) * 33 + b] + b_ih[512 + gb]  + b_hh[512 + gb];
                float ov = U[(3 * 32 + hlc) * 33 + b] + b_ih[768 + gb]  + b_hh[768 + gb];
                size_t cidx = (size_t)gb * 1024 + bg0 + b;
                float c_old = cx[cidx];
                float c_new = fmaf(sigmoidf_(fv), c_old, sigmoidf_(iv) * tanhf(gv));
                cx[cidx] = c_new;
                float hv = sigmoidf_(ov) * tanhf(c_new);
                cvt_hl(hv, hh[q], hl[q]);
            }
            size_t ho = (size_t)(bg0 + b) * 256 + hj * 32 + hq * 4;
            *(ushort4*)&hxh_out[ho] = make_ushort4(hh[0], hh[1], hh[2], hh[3]);
            *(ushort4*)&hxl_out[ho] = make_ushort4(hl[0], hl[1], hl[2], hl[3]);
        }
    }
}

extern "C" void kernel_launch(void* const* d_in, const int* in_sizes, int n_in,
                              void* d_out, int out_size, void* d_ws, size_t ws_size,
                              hipStream_t stream) {
    const float* coords = (const float*)d_in[0];
    const float* pitch  = (const float*)d_in[1];
    const float* W_e1   = (const float*)d_in[2];
    const float* b_e1   = (const float*)d_in[3];
    const float* W_e2   = (const float*)d_in[4];
    const float* b_e2   = (const float*)d_in[5];
    const float* W_ih   = (const float*)d_in[6];
    const float* b_ih   = (const float*)d_in[7];
    const float* W_hh   = (const float*)d_in[8];
    const float* b_hh   = (const float*)d_in[9];
    const float* W_out  = (const float*)d_in[10];
    const float* b_out  = (const float*)d_in[11];
    float* out = (float*)d_out;
    float* ws  = (float*)d_ws;

    // ws layout (float offsets); total ~19.3M floats ~= 77 MB
    float* cxb = ws;                                          // 262144
    unsigned short* hxhA = (unsigned short*)(ws + 262144);    // 131072 f
    unsigned short* hxlA = (unsigned short*)(ws + 393216);    // 131072 f
    unsigned short* hxhB = (unsigned short*)(ws + 524288);    // 131072 f
    unsigned short* hxlB = (unsigned short*)(ws + 655360);    // 131072 f
    unsigned short* Wt_h = (unsigned short*)(ws + 786432);    // 229376 f
    unsigned short* Wt_l = (unsigned short*)(ws + 1015808);   // 229376 f
    unsigned short* Wt_oh = (unsigned short*)(ws + 1245184);  // 16384 f
    unsigned short* Wt_ol = (unsigned short*)(ws + 1261568);  // 16384 f
    unsigned short* xin_h = (unsigned short*)(ws + 1277952);  // 18022400 f

    // zero cx + hxhA + hxlA (poisoned 0xAA by harness)
    hipMemsetAsync(ws, 0, (size_t)524288 * sizeof(float), stream);

    prep_wt<<<1024, 256, 0, stream>>>(W_ih, W_hh, Wt_h, Wt_l);
    prep_wo<<<128, 256, 0, stream>>>(W_out, Wt_oh, Wt_ol);
    enc_kernel<<<SEQ * 32, 256, 0, stream>>>(coords, W_e1, b_e1, W_e2, b_e2, xin_h);

    for (int t = 0; t <= SEQ; t++) {
        bool even = !(t & 1);
        step_kernel<<<256, 512, 0, stream>>>(
            t, xin_h,
            even ? hxhA : hxhB, even ? hxlA : hxlB,
            even ? hxhB : hxhA, even ? hxlB : hxlA,
            cxb, Wt_h, Wt_l, Wt_oh, Wt_ol, b_ih, b_hh, b_out, pitch, out);
    }
}